// Round 10
// baseline (4194.750 us; speedup 1.0000x reference)
//
#include <hip/hip_runtime.h>
#include <hip/hip_bf16.h>

#define VOCAB 32000
#define HID 512
#define BATCH 256
#define SEQ 128
#define NL 5
#define BH (BATCH*HID)      // 131072
#define G4H (4*HID)         // 2048
#define NBLK 160            // 5 layers x 32 column-slices, 1 block/CU

// byte strides in h ring: [slot][layer][j(32)][m(256)][c(16)] bf16
#define LAYB  (32*256*16*2)          // 262144 B per (slot,layer) slice
#define SLOTB (NL*LAYB)              // 1310720 B per slot
#define NSLOT 24                     // ring depth: 31.46 MB in d_out scratch

typedef __attribute__((ext_vector_type(8))) short short8;
typedef __attribute__((ext_vector_type(4))) float float4v;
typedef __attribute__((ext_vector_type(4))) unsigned int uint4v;

__device__ __forceinline__ float sigmoid_f(float x) {
    return 1.f / (1.f + __expf(-x));
}
__device__ __forceinline__ float tanh_f(float x) {
    float ax = fabsf(x);
    float e = __expf(2.f * ax);
    float t = 1.f - 2.f / (e + 1.f);
    return copysignf(t, x);
}
__device__ __forceinline__ short bf16bits(float f) {
    union { __hip_bfloat16 b; short s; } u;
    u.b = __float2bfloat16(f);
    return u.s;
}
__device__ __forceinline__ short8 load8f(const float* p) {   // fp32 -> bf16 frag
    float4v lo = *(const float4v*)p;
    float4v hi = *(const float4v*)(p + 4);
    short8 r;
    r[0] = bf16bits(lo[0]); r[1] = bf16bits(lo[1]);
    r[2] = bf16bits(lo[2]); r[3] = bf16bits(lo[3]);
    r[4] = bf16bits(hi[0]); r[5] = bf16bits(hi[1]);
    r[6] = bf16bits(hi[2]); r[7] = bf16bits(hi[3]);
    return r;
}
__device__ __forceinline__ short8 load8b(const __hip_bfloat16* p) {
    return *(const short8*)p;
}

// ---------------------------------------------------------------------------
// sc0|sc1 (=17) raw buffer STORES: write-through to the coherence point
// (LLC) -> ring is always LLC-current. Consumer loads are PLAIN CACHED
// (R9-verified: staleness impossible under the 24-slot write-once ring).
// ---------------------------------------------------------------------------
#if __has_builtin(__builtin_amdgcn_make_buffer_rsrc) && \
    __has_builtin(__builtin_amdgcn_raw_buffer_store_b128)
typedef __amdgpu_buffer_rsrc_t srd_t;
__device__ __forceinline__ srd_t make_srd(const void* p) {
    return __builtin_amdgcn_make_buffer_rsrc(const_cast<void*>(p), (short)0,
                                             0xFFFFFFFFu, 0x00020000);
}
__device__ __forceinline__ void bstore16(short8 v, srd_t srd, int voff) {
    union { uint4v u; short8 s; } c; c.s = v;
    __builtin_amdgcn_raw_buffer_store_b128(c.u, srd, voff, 0, 17);
}
#else
typedef const char* srd_t;
__device__ __forceinline__ srd_t make_srd(const void* p) {
    return (const char*)p;
}
__device__ __forceinline__ void bstore16(short8 v, srd_t srd, int voff) {
    char* base = const_cast<char*>(srd) + voff;
    union { unsigned long long q[2]; short8 s; } u; u.s = v;
    __hip_atomic_store((unsigned long long*)base, u.q[0],
                       __ATOMIC_RELAXED, __HIP_MEMORY_SCOPE_AGENT);
    __hip_atomic_store((unsigned long long*)(base + 8), u.q[1],
                       __ATOMIC_RELAXED, __HIP_MEMORY_SCOPE_AGENT);
}
#endif

// plain cached 16B ring load (L2-allocating)
__device__ __forceinline__ short8 rload16(const char* hb, int voff) {
    return *(const short8*)(hb + voff);
}

__host__ __device__ constexpr size_t hidx(int s, int l, int j, int m, int c) {
    return ((((size_t)s * NL + l) * 32 + j) * 256 + m) * 16 + c;
}

// flags: one int per (layer, j), spread 64B apart; release-stored.
#define FLAGI(l, j) (((l) * 32 + (j)) << 4)

// ---------------------------------------------------------------------------
// init: h0 fp32 -> bf16 ring slot 0 (d_out scratch); zero flag region
// ---------------------------------------------------------------------------
__global__ void init_state_k(const float* __restrict__ h0,
                             __hip_bfloat16* __restrict__ hring,
                             int* __restrict__ flags) {
    int i = blockIdx.x * 256 + threadIdx.x;   // grid covers NL*BH exactly
    int l = i / BH, r = i % BH;
    int m = r >> 9, col = r & 511;
    hring[hidx(0, l, col >> 4, m, col & 15)] = __float2bfloat16(h0[i]);
    if (blockIdx.x < 10) flags[blockIdx.x * 256 + threadIdx.x] = 0;
}

// ---------------------------------------------------------------------------
// persistent wavefront LSTM. block = (layer l, 16-col slice j); 16 waves,
// wave w owns rows [16w,16w+16). Weights bf16 in LDS (128 KB, frag order).
// c in registers. Structure = R9 (24-slot write-once ring, plain cached
// consumer loads, 64B release flags, wave0 ballot poll, chunk stagger).
// Round-10 deltas, attacking the SERIAL-RTT chain:
//  - split-phase wait: poll fprev first, issue all 8 h_in loads, THEN poll
//    fown/WAR -> h_in load latency hides under the own-layer poll.
//  - depth-8 dual-stream rotation (16 loads in flight/wave vs 8): load
//    phase = 2 serial RTTs instead of 4. VGPR ~110 (must stay <=128 for
//    4 waves/SIMD).
//  - poll backoff s_sleep(2) (160 polling waves only).
// ---------------------------------------------------------------------------
__global__ __launch_bounds__(1024) void lstm_persist_k(
    const int* __restrict__ x,
    const float* __restrict__ emb,
    const float* __restrict__ W_ih,
    const float* __restrict__ W_hh,
    const float* __restrict__ b_ih,
    const float* __restrict__ b_hh,
    const float* __restrict__ c0,
    __hip_bfloat16* __restrict__ hring,   // ring (d_out scratch)
    __hip_bfloat16* __restrict__ hfin,    // final h for out_gemm (ws)
    int* __restrict__ flags)
{
    __shared__ short lw[65536];               // 128 KB weight slice
    __shared__ short8 xch[16][32];            // 8 KB per-wave store transpose

    const int tid = threadIdx.x;
    const int xcd = blockIdx.x & 7;
    const int ixc = blockIdx.x >> 3;
    const int slot = xcd * 20 + ixc;          // XCD-contiguous slots
    const int l = slot >> 5;                  // layer 0..4
    const int j = slot & 31;                  // col slice 0..31
    const int jbase = j << 4;
    const int off = j >> 1;                   // K-chunk stagger (0..15)

    const int wave = tid >> 6, lane = tid & 63;
    const int quad = lane >> 4, l16 = lane & 15;
    const int m16 = wave << 4;

    const float* Wg[2] = { W_ih + (size_t)l * G4H * HID,
                           W_hh + (size_t)l * G4H * HID };

    // ---- stage weight slice into LDS in fragment order ----
    for (int e = tid; e < 8192; e += 1024) {
        int row = e >> 6;
        int kc  = (e & 63) << 3;
        int gemm = row >> 6, r2 = row & 63, g = r2 >> 4, rl = r2 & 15;
        const float* src = Wg[gemm] + (size_t)(g * HID + jbase + rl) * HID + kc;
        short8 v = load8f(src);
        int kt = kc >> 5, q = (kc >> 3) & 3;
        int fragslot = ((gemm * 4 + g) * 16 + kt) * 64 + (q * 16 + rl);
        *(short8*)&lw[(size_t)fragslot * 8] = v;
    }

    // ---- per-lane persistent state ----
    const int jj = jbase + l16;
    float bias[4], c_r[4];
#pragma unroll
    for (int g = 0; g < 4; ++g)
        bias[g] = b_ih[l * G4H + g * HID + jj] + b_hh[l * G4H + g * HID + jj];
#pragma unroll
    for (int r = 0; r < 4; ++r)
        c_r[r] = c0[(size_t)l * BH + (size_t)(m16 + quad * 4 + r) * HID + jj];

    const short* lwb = lw + (size_t)lane * 8;
    const int shi = quad >> 1;                // slice parity from quad
    const int abyte = ((m16 + l16) * 16 + (quad & 1) * 8) * 2 + shi * 8192;
    const srd_t rsrd = make_srd(hring);
    const srd_t fsrd = make_srd(hfin);
    const char* hb = (const char*)hring;

    const int lane31 = lane & 31;
    const int fprev = FLAGI(l - 1, lane31);
    const int fown  = FLAGI(l, lane31);
    const int fnext = FLAGI(l + 1, lane31);
    int* fmy = flags + FLAGI(l, j);

    __syncthreads();

    int rsp = 0, rsn = 1;                     // t % NSLOT, (t+1) % NSLOT

    for (int t = 0; t < SEQ; ++t) {
        const int vin = rsn * SLOTB + (l - 1) * LAYB + abyte;  // l-1 h(t)
        short8 ai[8], ah[8];

        // ---- phase A: h_in dependency only; issue h_in loads early ----
        if (l > 0) {
            if (wave == 0) {
                for (;;) {
                    bool ok = true;
                    if (lane < 32)
                        ok = __hip_atomic_load(&flags[fprev], __ATOMIC_RELAXED,
                                               __HIP_MEMORY_SCOPE_AGENT) >= t + 1;
                    if (__all(ok)) break;
                    __builtin_amdgcn_s_sleep(2);
                }
            }
            __syncthreads();
#pragma unroll
            for (int d = 0; d < 8; ++d)
                ai[d] = rload16(hb, vin + ((d + off) & 15) * 16384);
        }

        // ---- phase B: own-layer + WAR (h_in loads in flight meanwhile) ----
        if (wave == 0) {
            for (;;) {
                bool ok = true;
                if (lane < 32) {
                    if (t > 0)
                        ok &= __hip_atomic_load(&flags[fown], __ATOMIC_RELAXED,
                                                __HIP_MEMORY_SCOPE_AGENT) >= t;
                    if (l < NL - 1 && t >= NSLOT)
                        ok &= __hip_atomic_load(&flags[fnext], __ATOMIC_RELAXED,
                                                __HIP_MEMORY_SCOPE_AGENT) >= t - (NSLOT - 1);
                }
                if (__all(ok)) break;
                __builtin_amdgcn_s_sleep(2);
            }
        }
        __syncthreads();

        const int vpr = rsp * SLOTB + l * LAYB + abyte;      // own layer h(t)
#pragma unroll
        for (int d = 0; d < 8; ++d)
            ah[d] = rload16(hb, vpr + ((d + off) & 15) * 16384);

        float4v acc[4];
#pragma unroll
        for (int g = 0; g < 4; ++g) acc[g] = (float4v){0.f, 0.f, 0.f, 0.f};

        if (l == 0) {
            int tok = x[t * BATCH + m16 + l16];
            const float* ar = emb + (size_t)tok * HID;
#pragma unroll
            for (int s = 0; s < 16; ++s) {
                const int c = (s + off) & 15;
                short8 a_in = load8f(ar + c * 32 + quad * 8);
                short8 a_h = ah[s & 7];
                if (s + 8 < 16)
                    ah[s & 7] = rload16(hb, vpr + ((s + 8 + off) & 15) * 16384);
#pragma unroll
                for (int g = 0; g < 4; ++g) {
                    short8 b0 = *(const short8*)(lwb + (size_t)(g * 16 + c) * 512);
                    short8 b1 = *(const short8*)(lwb + (size_t)((4 + g) * 16 + c) * 512);
                    acc[g] = __builtin_amdgcn_mfma_f32_16x16x32_bf16(a_in, b0, acc[g], 0, 0, 0);
                    acc[g] = __builtin_amdgcn_mfma_f32_16x16x32_bf16(a_h,  b1, acc[g], 0, 0, 0);
                }
            }
        } else {
#pragma unroll
            for (int s = 0; s < 16; ++s) {
                const int c = (s + off) & 15;
                short8 a_in = ai[s & 7];
                short8 a_h  = ah[s & 7];
                if (s + 8 < 16) {
                    const int cf = (s + 8 + off) & 15;
                    ai[s & 7] = rload16(hb, vin + cf * 16384);
                    ah[s & 7] = rload16(hb, vpr + cf * 16384);
                }
#pragma unroll
                for (int g = 0; g < 4; ++g) {
                    short8 b0 = *(const short8*)(lwb + (size_t)(g * 16 + c) * 512);
                    short8 b1 = *(const short8*)(lwb + (size_t)((4 + g) * 16 + c) * 512);
                    acc[g] = __builtin_amdgcn_mfma_f32_16x16x32_bf16(a_in, b0, acc[g], 0, 0, 0);
                    acc[g] = __builtin_amdgcn_mfma_f32_16x16x32_bf16(a_h,  b1, acc[g], 0, 0, 0);
                }
            }
        }

        // ---- epilogue: register c; per-wave LDS transpose of the 16x16
        //      output tile; 32 lanes x 16B sc1 write-through stores ----
        short* xp = (short*)&xch[wave];
#pragma unroll
        for (int r = 0; r < 4; ++r) {
            float iv = sigmoid_f(acc[0][r] + bias[0]);
            float fv = sigmoid_f(acc[1][r] + bias[1]);
            float gv = tanh_f(acc[2][r] + bias[2]);
            float ov = sigmoid_f(acc[3][r] + bias[3]);
            c_r[r] = fv * c_r[r] + iv * gv;
            xp[(quad * 4 + r) * 16 + l16] = bf16bits(ov * tanh_f(c_r[r]));
        }
        __builtin_amdgcn_wave_barrier();      // order LDS write -> read in-wave
        if (lane < 32) {
            short8 v = *(const short8*)&xp[lane * 8];
            int voutc = j * 8192 + m16 * 32 + lane * 16;   // within-slice bytes
            bstore16(v, rsrd, rsn * SLOTB + l * LAYB + voutc);
            if (l == NL - 1 && t == SEQ - 1)
                bstore16(v, fsrd, voutc);     // final h for out_gemm (ws)
        }

        __syncthreads();   // all waves' h stores drained (vmcnt) at barrier
        if (tid == 0)
            __hip_atomic_store(fmy, t + 1, __ATOMIC_RELEASE,
                               __HIP_MEMORY_SCOPE_AGENT);

        rsp = rsn;
        rsn = (rsn + 1 == NSLOT) ? 0 : rsn + 1;
    }
}

// ---------------------------------------------------------------------------
// output projection: out(256 x 32000) = h_final @ W_out^T + b_out
// 500 blocks x 512 thr; A = bf16 final h in ws ([j][m][c] slice layout),
// B = fp32 W_out streamed.
// ---------------------------------------------------------------------------
__global__ __launch_bounds__(512) void out_gemm_k(
    const __hip_bfloat16* __restrict__ hfin,
    const float* __restrict__ W_out,
    const float* __restrict__ b_out,
    float* __restrict__ out)
{
    const int nb = blockIdx.x;
    const int tid = threadIdx.x;
    const int wave = tid >> 6, lane = tid & 63;
    const int quad = lane >> 4, l16 = lane & 15;
    const int nt = wave & 3, mh = wave >> 2;

    const int shi = quad >> 1;
    const size_t coff = (size_t)(quad & 1) * 8;

    const int ncol = nb * 64 + nt * 16 + l16;
    const float* brow = W_out + (size_t)ncol * HID;

    float4v acc[8];
#pragma unroll
    for (int mt = 0; mt < 8; ++mt) acc[mt] = (float4v){0.f, 0.f, 0.f, 0.f};

#pragma unroll 2
    for (int kt = 0; kt < 16; ++kt) {
        short8 b = load8f(brow + kt * 32 + quad * 8);
        const __hip_bfloat16* abase =
            hfin + (size_t)(2 * kt + shi) * 4096 + coff;
#pragma unroll
        for (int mt = 0; mt < 8; ++mt) {
            short8 a = load8b(abase + (size_t)(mh * 128 + mt * 16 + l16) * 16);
            acc[mt] = __builtin_amdgcn_mfma_f32_16x16x32_bf16(a, b, acc[mt], 0, 0, 0);
        }
    }

    float bo = b_out[ncol];
#pragma unroll
    for (int mt = 0; mt < 8; ++mt) {
#pragma unroll
        for (int r = 0; r < 4; ++r) {
            int m = mh * 128 + mt * 16 + quad * 4 + r;
            out[(size_t)m * VOCAB + ncol] = acc[mt][r] + bo;
        }
    }
}

extern "C" void kernel_launch(void* const* d_in, const int* in_sizes, int n_in,
                              void* d_out, int out_size, void* d_ws, size_t ws_size,
                              hipStream_t stream) {
    const int* x        = (const int*)d_in[0];
    const float* h0     = (const float*)d_in[1];
    const float* c0     = (const float*)d_in[2];
    const float* emb    = (const float*)d_in[3];
    const float* W_ih   = (const float*)d_in[4];
    const float* W_hh   = (const float*)d_in[5];
    const float* b_ih   = (const float*)d_in[6];
    const float* b_hh   = (const float*)d_in[7];
    const float* W_out  = (const float*)d_in[8];
    const float* b_out  = (const float*)d_in[9];
    float* out          = (float*)d_out;

    // d_out scratch: 24-slot h ring (31.46 MB) + flags (10 KB) = 31.47 MB
    // < 32.77 MB out buffer; out_gemm fully overwrites d_out afterwards.
    // ws: final-h slice (1.31 MB) for out_gemm.
    __hip_bfloat16* hring = (__hip_bfloat16*)d_out;
    int* flags = (int*)((char*)d_out + (size_t)NSLOT * SLOTB);
    __hip_bfloat16* hfin = (__hip_bfloat16*)d_ws;

    init_state_k<<<(NL * BH) / 256, 256, 0, stream>>>(h0, hring, flags);

    lstm_persist_k<<<NBLK, 1024, 0, stream>>>(x, emb, W_ih, W_hh, b_ih, b_hh,
                                              c0, hring, hfin, flags);

    out_gemm_k<<<VOCAB / 64, 512, 0, stream>>>(hfin, W_out, b_out, out);
}

// Round 11
// 2919.314 us; speedup vs baseline: 1.4369x; 1.4369x over previous
//
#include <hip/hip_runtime.h>
#include <hip/hip_bf16.h>

#define VOCAB 32000
#define HID 512
#define BATCH 256
#define SEQ 128
#define NL 5
#define BH (BATCH*HID)      // 131072
#define G4H (4*HID)         // 2048
#define NBLK 160            // 5 layers x 32 column-slices, 1 block/CU

// byte strides in h ring: [slot][layer][j(32)][m(256)][c(16)] bf16
#define LAYB  (32*256*16*2)          // 262144 B per (slot,layer) slice
#define SLOTB (NL*LAYB)              // 1310720 B per slot
#define NSLOT 24                     // ring depth: 31.46 MB in d_out scratch

typedef __attribute__((ext_vector_type(8))) short short8;
typedef __attribute__((ext_vector_type(4))) float float4v;
typedef __attribute__((ext_vector_type(4))) unsigned int uint4v;

__device__ __forceinline__ float sigmoid_f(float x) {
    return 1.f / (1.f + __expf(-x));
}
__device__ __forceinline__ float tanh_f(float x) {
    float ax = fabsf(x);
    float e = __expf(2.f * ax);
    float t = 1.f - 2.f / (e + 1.f);
    return copysignf(t, x);
}
__device__ __forceinline__ short bf16bits(float f) {
    union { __hip_bfloat16 b; short s; } u;
    u.b = __float2bfloat16(f);
    return u.s;
}
__device__ __forceinline__ short8 load8f(const float* p) {   // fp32 -> bf16 frag
    float4v lo = *(const float4v*)p;
    float4v hi = *(const float4v*)(p + 4);
    short8 r;
    r[0] = bf16bits(lo[0]); r[1] = bf16bits(lo[1]);
    r[2] = bf16bits(lo[2]); r[3] = bf16bits(lo[3]);
    r[4] = bf16bits(hi[0]); r[5] = bf16bits(hi[1]);
    r[6] = bf16bits(hi[2]); r[7] = bf16bits(hi[3]);
    return r;
}
__device__ __forceinline__ short8 load8b(const __hip_bfloat16* p) {
    return *(const short8*)p;
}

// ---------------------------------------------------------------------------
// sc0|sc1 (=17) raw buffer STORES: write-through to the coherence point
// (LLC) -> ring is always LLC-current. Consumer loads are PLAIN CACHED
// (R9-verified: staleness impossible under the 24-slot write-once ring).
// ---------------------------------------------------------------------------
#if __has_builtin(__builtin_amdgcn_make_buffer_rsrc) && \
    __has_builtin(__builtin_amdgcn_raw_buffer_store_b128)
typedef __amdgpu_buffer_rsrc_t srd_t;
__device__ __forceinline__ srd_t make_srd(const void* p) {
    return __builtin_amdgcn_make_buffer_rsrc(const_cast<void*>(p), (short)0,
                                             0xFFFFFFFFu, 0x00020000);
}
__device__ __forceinline__ void bstore16(short8 v, srd_t srd, int voff) {
    union { uint4v u; short8 s; } c; c.s = v;
    __builtin_amdgcn_raw_buffer_store_b128(c.u, srd, voff, 0, 17);
}
#else
typedef const char* srd_t;
__device__ __forceinline__ srd_t make_srd(const void* p) {
    return (const char*)p;
}
__device__ __forceinline__ void bstore16(short8 v, srd_t srd, int voff) {
    char* base = const_cast<char*>(srd) + voff;
    union { unsigned long long q[2]; short8 s; } u; u.s = v;
    __hip_atomic_store((unsigned long long*)base, u.q[0],
                       __ATOMIC_RELAXED, __HIP_MEMORY_SCOPE_AGENT);
    __hip_atomic_store((unsigned long long*)(base + 8), u.q[1],
                       __ATOMIC_RELAXED, __HIP_MEMORY_SCOPE_AGENT);
}
#endif

// plain cached 16B ring load (L2-allocating)
__device__ __forceinline__ short8 rload16(const char* hb, int voff) {
    return *(const short8*)(hb + voff);
}

__host__ __device__ constexpr size_t hidx(int s, int l, int j, int m, int c) {
    return ((((size_t)s * NL + l) * 32 + j) * 256 + m) * 16 + c;
}

// flags: one int per (layer, j), spread 64B apart; release-stored.
#define FLAGI(l, j) (((l) * 32 + (j)) << 4)

// ---------------------------------------------------------------------------
// init: h0 fp32 -> bf16 ring slot 0 (d_out scratch); zero flag region
// ---------------------------------------------------------------------------
__global__ void init_state_k(const float* __restrict__ h0,
                             __hip_bfloat16* __restrict__ hring,
                             int* __restrict__ flags) {
    int i = blockIdx.x * 256 + threadIdx.x;   // grid covers NL*BH exactly
    int l = i / BH, r = i % BH;
    int m = r >> 9, col = r & 511;
    hring[hidx(0, l, col >> 4, m, col & 15)] = __float2bfloat16(h0[i]);
    if (blockIdx.x < 10) flags[blockIdx.x * 256 + threadIdx.x] = 0;
}

// ---------------------------------------------------------------------------
// persistent wavefront LSTM. block = (layer l, 16-col slice j); 16 waves,
// wave w owns rows [16w,16w+16). Weights bf16 in LDS (128 KB, frag order).
// c in registers. Structure = R9 (24-slot write-once ring, plain cached
// consumer loads, 64B release flags, wave0 ballot poll, chunk stagger).
// R11 = R10's serial-RTT attack done WITHOUT scratch spill:
//  - whole step body is ONE l==0/l>0 branch (l block-uniform; inner
//    __syncthreads convergent) -> ai[8]/ah[8] live in a single scope with
//    constant indices -> promoted to VGPRs (R10 spilled: VGPR stuck at 64,
//    FETCH 6x, WRITE 12x = scratch traffic).
//  - __launch_bounds__(1024, 4): 4 waves/EU -> 128-VGPR budget; LDS already
//    pins 1 block/CU so occupancy is unchanged.
//  - split-phase wait: poll fprev -> issue 8 h_in loads -> poll fown/WAR ->
//    8 h_prev loads -> depth-8 rotation (2 serial RTTs in the load stream).
// ---------------------------------------------------------------------------
__global__ __launch_bounds__(1024, 4) void lstm_persist_k(
    const int* __restrict__ x,
    const float* __restrict__ emb,
    const float* __restrict__ W_ih,
    const float* __restrict__ W_hh,
    const float* __restrict__ b_ih,
    const float* __restrict__ b_hh,
    const float* __restrict__ c0,
    __hip_bfloat16* __restrict__ hring,   // ring (d_out scratch)
    __hip_bfloat16* __restrict__ hfin,    // final h for out_gemm (ws)
    int* __restrict__ flags)
{
    __shared__ short lw[65536];               // 128 KB weight slice
    __shared__ short8 xch[16][32];            // 8 KB per-wave store transpose

    const int tid = threadIdx.x;
    const int xcd = blockIdx.x & 7;
    const int ixc = blockIdx.x >> 3;
    const int slot = xcd * 20 + ixc;          // XCD-contiguous slots
    const int l = slot >> 5;                  // layer 0..4
    const int j = slot & 31;                  // col slice 0..31
    const int jbase = j << 4;
    const int off = j >> 1;                   // K-chunk stagger (0..15)

    const int wave = tid >> 6, lane = tid & 63;
    const int quad = lane >> 4, l16 = lane & 15;
    const int m16 = wave << 4;

    const float* Wg[2] = { W_ih + (size_t)l * G4H * HID,
                           W_hh + (size_t)l * G4H * HID };

    // ---- stage weight slice into LDS in fragment order ----
    for (int e = tid; e < 8192; e += 1024) {
        int row = e >> 6;
        int kc  = (e & 63) << 3;
        int gemm = row >> 6, r2 = row & 63, g = r2 >> 4, rl = r2 & 15;
        const float* src = Wg[gemm] + (size_t)(g * HID + jbase + rl) * HID + kc;
        short8 v = load8f(src);
        int kt = kc >> 5, q = (kc >> 3) & 3;
        int fragslot = ((gemm * 4 + g) * 16 + kt) * 64 + (q * 16 + rl);
        *(short8*)&lw[(size_t)fragslot * 8] = v;
    }

    // ---- per-lane persistent state ----
    const int jj = jbase + l16;
    float bias[4], c_r[4];
#pragma unroll
    for (int g = 0; g < 4; ++g)
        bias[g] = b_ih[l * G4H + g * HID + jj] + b_hh[l * G4H + g * HID + jj];
#pragma unroll
    for (int r = 0; r < 4; ++r)
        c_r[r] = c0[(size_t)l * BH + (size_t)(m16 + quad * 4 + r) * HID + jj];

    const short* lwb = lw + (size_t)lane * 8;
    const int shi = quad >> 1;                // slice parity from quad
    const int abyte = ((m16 + l16) * 16 + (quad & 1) * 8) * 2 + shi * 8192;
    const srd_t rsrd = make_srd(hring);
    const srd_t fsrd = make_srd(hfin);
    const char* hb = (const char*)hring;

    const int lane31 = lane & 31;
    const int fprev = FLAGI(l - 1, lane31);
    const int fown  = FLAGI(l, lane31);
    const int fnext = FLAGI(l + 1, lane31);
    int* fmy = flags + FLAGI(l, j);

    __syncthreads();

    int rsp = 0, rsn = 1;                     // t % NSLOT, (t+1) % NSLOT

    for (int t = 0; t < SEQ; ++t) {
        const int vpr = rsp * SLOTB + l * LAYB + abyte;      // own layer h(t)

        float4v acc[4];
#pragma unroll
        for (int g = 0; g < 4; ++g) acc[g] = (float4v){0.f, 0.f, 0.f, 0.f};

        if (l == 0) {
            // ---- wait: own-layer + WAR ----
            if (wave == 0) {
                for (;;) {
                    bool ok = true;
                    if (lane < 32) {
                        if (t > 0)
                            ok &= __hip_atomic_load(&flags[fown], __ATOMIC_RELAXED,
                                                    __HIP_MEMORY_SCOPE_AGENT) >= t;
                        if (t >= NSLOT)
                            ok &= __hip_atomic_load(&flags[fnext], __ATOMIC_RELAXED,
                                                    __HIP_MEMORY_SCOPE_AGENT) >= t - (NSLOT - 1);
                    }
                    if (__all(ok)) break;
                    __builtin_amdgcn_s_sleep(2);
                }
            }
            __syncthreads();

            short8 ah[8];
#pragma unroll
            for (int d = 0; d < 8; ++d)
                ah[d] = rload16(hb, vpr + ((d + off) & 15) * 16384);

            int tok = x[t * BATCH + m16 + l16];
            const float* ar = emb + (size_t)tok * HID;
#pragma unroll
            for (int s = 0; s < 16; ++s) {
                const int c = (s + off) & 15;
                short8 a_in = load8f(ar + c * 32 + quad * 8);
                short8 a_h = ah[s & 7];
                if (s + 8 < 16)
                    ah[s & 7] = rload16(hb, vpr + ((s + 8 + off) & 15) * 16384);
#pragma unroll
                for (int g = 0; g < 4; ++g) {
                    short8 b0 = *(const short8*)(lwb + (size_t)(g * 16 + c) * 512);
                    short8 b1 = *(const short8*)(lwb + (size_t)((4 + g) * 16 + c) * 512);
                    acc[g] = __builtin_amdgcn_mfma_f32_16x16x32_bf16(a_in, b0, acc[g], 0, 0, 0);
                    acc[g] = __builtin_amdgcn_mfma_f32_16x16x32_bf16(a_h,  b1, acc[g], 0, 0, 0);
                }
            }
        } else {
            // ---- phase A: h_in dependency only; issue h_in loads early ----
            if (wave == 0) {
                for (;;) {
                    bool ok = true;
                    if (lane < 32)
                        ok = __hip_atomic_load(&flags[fprev], __ATOMIC_RELAXED,
                                               __HIP_MEMORY_SCOPE_AGENT) >= t + 1;
                    if (__all(ok)) break;
                    __builtin_amdgcn_s_sleep(2);
                }
            }
            __syncthreads();

            const int vin = rsn * SLOTB + (l - 1) * LAYB + abyte;  // l-1 h(t)
            short8 ai[8];
#pragma unroll
            for (int d = 0; d < 8; ++d)
                ai[d] = rload16(hb, vin + ((d + off) & 15) * 16384);

            // ---- phase B: own-layer + WAR (h_in loads fly meanwhile) ----
            if (wave == 0) {
                for (;;) {
                    bool ok = true;
                    if (lane < 32) {
                        if (t > 0)
                            ok &= __hip_atomic_load(&flags[fown], __ATOMIC_RELAXED,
                                                    __HIP_MEMORY_SCOPE_AGENT) >= t;
                        if (l < NL - 1 && t >= NSLOT)
                            ok &= __hip_atomic_load(&flags[fnext], __ATOMIC_RELAXED,
                                                    __HIP_MEMORY_SCOPE_AGENT) >= t - (NSLOT - 1);
                    }
                    if (__all(ok)) break;
                    __builtin_amdgcn_s_sleep(2);
                }
            }
            __syncthreads();

            short8 ah[8];
#pragma unroll
            for (int d = 0; d < 8; ++d)
                ah[d] = rload16(hb, vpr + ((d + off) & 15) * 16384);

#pragma unroll
            for (int s = 0; s < 16; ++s) {
                const int c = (s + off) & 15;
                short8 a_in = ai[s & 7];
                short8 a_h  = ah[s & 7];
                if (s + 8 < 16) {
                    const int cf = (s + 8 + off) & 15;
                    ai[s & 7] = rload16(hb, vin + cf * 16384);
                    ah[s & 7] = rload16(hb, vpr + cf * 16384);
                }
#pragma unroll
                for (int g = 0; g < 4; ++g) {
                    short8 b0 = *(const short8*)(lwb + (size_t)(g * 16 + c) * 512);
                    short8 b1 = *(const short8*)(lwb + (size_t)((4 + g) * 16 + c) * 512);
                    acc[g] = __builtin_amdgcn_mfma_f32_16x16x32_bf16(a_in, b0, acc[g], 0, 0, 0);
                    acc[g] = __builtin_amdgcn_mfma_f32_16x16x32_bf16(a_h,  b1, acc[g], 0, 0, 0);
                }
            }
        }

        // ---- epilogue: register c; per-wave LDS transpose of the 16x16
        //      output tile; 32 lanes x 16B sc1 write-through stores ----
        short* xp = (short*)&xch[wave];
#pragma unroll
        for (int r = 0; r < 4; ++r) {
            float iv = sigmoid_f(acc[0][r] + bias[0]);
            float fv = sigmoid_f(acc[1][r] + bias[1]);
            float gv = tanh_f(acc[2][r] + bias[2]);
            float ov = sigmoid_f(acc[3][r] + bias[3]);
            c_r[r] = fv * c_r[r] + iv * gv;
            xp[(quad * 4 + r) * 16 + l16] = bf16bits(ov * tanh_f(c_r[r]));
        }
        __builtin_amdgcn_wave_barrier();      // order LDS write -> read in-wave
        if (lane < 32) {
            short8 v = *(const short8*)&xp[lane * 8];
            int voutc = j * 8192 + m16 * 32 + lane * 16;   // within-slice bytes
            bstore16(v, rsrd, rsn * SLOTB + l * LAYB + voutc);
            if (l == NL - 1 && t == SEQ - 1)
                bstore16(v, fsrd, voutc);     // final h for out_gemm (ws)
        }

        __syncthreads();   // all waves' h stores drained (vmcnt) at barrier
        if (tid == 0)
            __hip_atomic_store(fmy, t + 1, __ATOMIC_RELEASE,
                               __HIP_MEMORY_SCOPE_AGENT);

        rsp = rsn;
        rsn = (rsn + 1 == NSLOT) ? 0 : rsn + 1;
    }
}

// ---------------------------------------------------------------------------
// output projection: out(256 x 32000) = h_final @ W_out^T + b_out
// 500 blocks x 512 thr; A = bf16 final h in ws ([j][m][c] slice layout),
// B = fp32 W_out streamed.
// ---------------------------------------------------------------------------
__global__ __launch_bounds__(512) void out_gemm_k(
    const __hip_bfloat16* __restrict__ hfin,
    const float* __restrict__ W_out,
    const float* __restrict__ b_out,
    float* __restrict__ out)
{
    const int nb = blockIdx.x;
    const int tid = threadIdx.x;
    const int wave = tid >> 6, lane = tid & 63;
    const int quad = lane >> 4, l16 = lane & 15;
    const int nt = wave & 3, mh = wave >> 2;

    const int shi = quad >> 1;
    const size_t coff = (size_t)(quad & 1) * 8;

    const int ncol = nb * 64 + nt * 16 + l16;
    const float* brow = W_out + (size_t)ncol * HID;

    float4v acc[8];
#pragma unroll
    for (int mt = 0; mt < 8; ++mt) acc[mt] = (float4v){0.f, 0.f, 0.f, 0.f};

#pragma unroll 2
    for (int kt = 0; kt < 16; ++kt) {
        short8 b = load8f(brow + kt * 32 + quad * 8);
        const __hip_bfloat16* abase =
            hfin + (size_t)(2 * kt + shi) * 4096 + coff;
#pragma unroll
        for (int mt = 0; mt < 8; ++mt) {
            short8 a = load8b(abase + (size_t)(mh * 128 + mt * 16 + l16) * 16);
            acc[mt] = __builtin_amdgcn_mfma_f32_16x16x32_bf16(a, b, acc[mt], 0, 0, 0);
        }
    }

    float bo = b_out[ncol];
#pragma unroll
    for (int mt = 0; mt < 8; ++mt) {
#pragma unroll
        for (int r = 0; r < 4; ++r) {
            int m = mh * 128 + mt * 16 + quad * 4 + r;
            out[(size_t)m * VOCAB + ncol] = acc[mt][r] + bo;
        }
    }
}

extern "C" void kernel_launch(void* const* d_in, const int* in_sizes, int n_in,
                              void* d_out, int out_size, void* d_ws, size_t ws_size,
                              hipStream_t stream) {
    const int* x        = (const int*)d_in[0];
    const float* h0     = (const float*)d_in[1];
    const float* c0     = (const float*)d_in[2];
    const float* emb    = (const float*)d_in[3];
    const float* W_ih   = (const float*)d_in[4];
    const float* W_hh   = (const float*)d_in[5];
    const float* b_ih   = (const float*)d_in[6];
    const float* b_hh   = (const float*)d_in[7];
    const float* W_out  = (const float*)d_in[8];
    const float* b_out  = (const float*)d_in[9];
    float* out          = (float*)d_out;

    // d_out scratch: 24-slot h ring (31.46 MB) + flags (10 KB) = 31.47 MB
    // < 32.77 MB out buffer; out_gemm fully overwrites d_out afterwards.
    // ws: final-h slice (1.31 MB) for out_gemm.
    __hip_bfloat16* hring = (__hip_bfloat16*)d_out;
    int* flags = (int*)((char*)d_out + (size_t)NSLOT * SLOTB);
    __hip_bfloat16* hfin = (__hip_bfloat16*)d_ws;

    init_state_k<<<(NL * BH) / 256, 256, 0, stream>>>(h0, hring, flags);

    lstm_persist_k<<<NBLK, 1024, 0, stream>>>(x, emb, W_ih, W_hh, b_ih, b_hh,
                                              c0, hring, hfin, flags);

    out_gemm_k<<<VOCAB / 64, 512, 0, stream>>>(hfin, W_out, b_out, out);
}